// Round 13
// baseline (9093.096 us; speedup 1.0000x reference)
//
#include <hip/hip_runtime.h>
#include <stdint.h>

// ---------------- problem constants ----------------
#define H      2048
#define SEQ    1024
#define NB     256      // persistent blocks (1 per CU)
#define NT     512      // threads per block (8 waves)
#define JPB    8        // hidden units per block per layer (H / NB)
#define ROUNDS (SEQ + 1)
#define LIMG   (1 << 11)   // global-spin bail (~1ms; each iter ~ a load latency)
#define LIML   (1 << 15)   // LDS-spin bail

typedef _Float16 f16;
typedef _Float16 f16x2 __attribute__((ext_vector_type(2)));
typedef unsigned int u32;
typedef unsigned long long u64;
typedef unsigned short u16;

// ---------------- workspace layout (bytes) ----------------
static const size_t H0_OFF  = 4096;
static const size_t HBYTES  = (size_t)(SEQ + 2) * H * 2;   // 4,202,496
static const size_t H1_OFF  = H0_OFF + HBYTES;
static const size_t WS_NEED = H1_OFF + HBYTES;             // ~8.4 MB

// ---------------- LDS layout (bytes) ----------------
//     0..10239 : hs0[2][5120]  (h0 stage, 80B-pad rows, dbuf r&1)
// 10240..20479 : hs1[2][5120]
// 20480..20543 : hres0[2][8] u32 ; 20544..20607 : hres1[2][8] u32
// 20608 fstage0 ; 20612 fstage1 ; 20616 fgath0[8] ; 20648 fgath1[8]
// 20680 fdone[8] ; 20712 dead
#define LDS_BYTES 20736

// ---------------- helpers ----------------
__device__ __forceinline__ u32 pk2(float a, float b) {
  f16x2 h; h.x = (f16)a; h.y = (f16)b;
  return __builtin_bit_cast(u32, h);
}

__device__ __forceinline__ float dot2(u32 a, u32 b, float c) {
#if __has_builtin(__builtin_amdgcn_fdot2)
  return __builtin_amdgcn_fdot2(__builtin_bit_cast(f16x2, a),
                                __builtin_bit_cast(f16x2, b), c, false);
#else
  f16x2 av = __builtin_bit_cast(f16x2, a);
  f16x2 bv = __builtin_bit_cast(f16x2, b);
  return c + (float)av.x * (float)bv.x + (float)av.y * (float)bv.y;
#endif
}

template <int CTRL>
__device__ __forceinline__ float dppadd(float x) {
  int y = __builtin_amdgcn_update_dpp(0, __float_as_int(x), CTRL, 0xF, 0xF, false);
  return x + __int_as_float(y);
}
__device__ __forceinline__ float wave_reduce63(float x) {
  x = dppadd<0x111>(x); x = dppadd<0x112>(x); x = dppadd<0x114>(x);
  x = dppadd<0x118>(x); x = dppadd<0x142>(x); x = dppadd<0x143>(x);
  return x;   // total in lane 63
}

__device__ __forceinline__ float sigm(float x) { return 1.0f / (1.0f + __expf(-x)); }
__device__ __forceinline__ float tanh_(float x) {
  float t = __expf(-2.0f * fabsf(x));
  float r = (1.0f - t) / (1.0f + t);
  return copysignf(r, x);
}

// any u16 half equals 0x7C00 (f16 +inf sentinel)? produced |h|<1 -> never 0x7C00
__device__ __forceinline__ bool has_sent(u64 v) {
  const u64 x = v ^ 0x7C007C007C007C00ull;
  return ((x - 0x0001000100010001ull) & ~x & 0x8000800080008000ull) != 0ull;
}

// verify 8 pre-issued u64 snapshots of one h row-slice; reload stale lanes
__device__ __forceinline__ void verify8(u64 v[8], const u64* base, int lane, u32* dead) {
  int it = 0;
  while (true) {
    bool all = true;
    #pragma unroll
    for (int k = 0; k < 8; ++k)
      if (has_sent(v[k])) {
        all = false;
        v[k] = __hip_atomic_load(base + k * 64 + lane, __ATOMIC_RELAXED, __HIP_MEMORY_SCOPE_AGENT);
      }
    if (all) break;
    if (*(volatile u32*)dead) break;
    if (++it > LIMG) { *(volatile u32*)dead = 1; break; }
    __builtin_amdgcn_s_sleep(1);
  }
}

__device__ __forceinline__ void lds_spin_ge(u32* f, u32 val, u32* dead) {
  int it = 0;
  while (__hip_atomic_load(f, __ATOMIC_ACQUIRE, __HIP_MEMORY_SCOPE_WORKGROUP) < val) {
    if (*(volatile u32*)dead) break;
    if (++it > LIML) { *(volatile u32*)dead = 1; break; }
  }
}
__device__ __forceinline__ void lds_spin8_ge(u32* f, u32 val, u32* dead) {
  int it = 0;
  while (true) {
    bool ok = true;
    #pragma unroll
    for (int w = 0; w < 8; ++w)
      ok &= (__hip_atomic_load(f + w, __ATOMIC_ACQUIRE, __HIP_MEMORY_SCOPE_WORKGROUP) >= val);
    if (ok) break;
    if (*(volatile u32*)dead) break;
    if (++it > LIML) { *(volatile u32*)dead = 1; break; }
  }
}

// ---------------- init kernel: sentinel-fill h buffers, write initial states ----------------
#define PER_BUF_U32 ((SEQ + 1) * (H / 2))
__global__ void lstm_init(const float* __restrict__ h0in, unsigned char* __restrict__ wsb) {
  const int i = blockIdx.x * blockDim.x + threadIdx.x;
  u32* b0 = (u32*)(wsb + H0_OFF);
  u32* b1 = (u32*)(wsb + H1_OFF);
  if (i < H / 2) {
    b0[i] = pk2(h0in[2 * i], h0in[2 * i + 1]);
    b1[i] = pk2(h0in[H + 2 * i], h0in[H + 2 * i + 1]);
  } else if (i < PER_BUF_U32) {
    b0[i] = 0x7C007C00u;
    b1[i] = 0x7C007C00u;
  }
}

// ---------------- persistent LSTM: wave-autonomous, zero in-loop barriers ----------------
// Round r per wave: L0 compute -> [w2: publish h0[r+1]] -> [w1: stage h1[r-1]]
// -> L1 compute -> [w3: publish h1[r]] -> fdone -> [w0: EARLY-stage h0[r+1]].
// fstage0 for round r+1 is set during round r, so L0 starts with zero detect.
__global__ __launch_bounds__(NT, 1) void lstm_pers(
    const float* __restrict__ xin,   // [SEQ,2]
    const float* __restrict__ c0in,  // [2,1,H]
    const float* __restrict__ Wih0,  // [4H,2]
    const float* __restrict__ Whh0,  // [4H,H]
    const float* __restrict__ bih0,
    const float* __restrict__ bhh0,
    const float* __restrict__ Wih1,  // [4H,H]
    const float* __restrict__ Whh1,  // [4H,H]
    const float* __restrict__ bih1,
    const float* __restrict__ bhh1,
    unsigned char* __restrict__ wsb)
{
  const int b    = blockIdx.x;
  const int tid  = threadIdx.x;
  const int lane = tid & 63;
  const int wave = tid >> 6;

  f16* h0b = (f16*)(wsb + H0_OFF);
  f16* h1b = (f16*)(wsb + H1_OFF);

  __shared__ __align__(16) unsigned char smem[LDS_BYTES];
  u32* hres0   = (u32*)(smem + 20480);   // [2][8]
  u32* hres1   = (u32*)(smem + 20544);   // [2][8]
  u32* fstage0 = (u32*)(smem + 20608);
  u32* fstage1 = (u32*)(smem + 20612);
  u32* fgath0  = (u32*)(smem + 20616);   // [8]
  u32* fgath1  = (u32*)(smem + 20648);   // [8]
  u32* fdone   = (u32*)(smem + 20680);   // [8]
  u32* dead    = (u32*)(smem + 20712);

  if (tid < 32) ((u32*)(smem + 20608))[tid] = 0;   // zero flags + dead

  // ---- per-unit constants (unit u = b*8 + wave; lane 63 uses them) ----
  const int u = b * JPB + wave;
  float wx0[4], wx1[4], bs0[4], bs1[4];
  #pragma unroll
  for (int m = 0; m < 4; ++m) {
    const int R = m * H + u;
    wx0[m] = Wih0[(size_t)R * 2];
    wx1[m] = Wih0[(size_t)R * 2 + 1];
    bs0[m] = bih0[R] + bhh0[R];
    bs1[m] = bih1[R] + bhh1[R];
  }
  float c0st = c0in[u];
  float c1st = c0in[H + u];

  // ---- weights: wave owns unit u for all 3 matrices (12 rows, 192 u32) ----
  u32 wgt[4][3][16];
  {
    #pragma unroll
    for (int m = 0; m < 4; ++m) {
      const int R = m * H + u;
      const float* srcs[3] = { Whh0 + (size_t)R * H, Wih1 + (size_t)R * H, Whh1 + (size_t)R * H };
      #pragma unroll
      for (int mat = 0; mat < 3; ++mat) {
        const float4* s4 = (const float4*)(srcs[mat] + lane * 32);
        #pragma unroll
        for (int i = 0; i < 8; ++i) {
          float4 f = s4[i];
          wgt[m][mat][2 * i]     = pk2(f.x, f.y);
          wgt[m][mat][2 * i + 1] = pk2(f.z, f.w);
        }
        __builtin_amdgcn_sched_barrier(0);
      }
    }
  }
  __syncthreads();   // startup only: flags zeroed + weights loaded

  u64 v0[8], v1[8];
  // pre-loop: wave0 stages h0[0] (init-ready) -> fstage0 = 1
  if (wave == 0) {
    #pragma unroll
    for (int k = 0; k < 8; ++k)
      v0[k] = __hip_atomic_load((const u64*)h0b + k * 64 + lane, __ATOMIC_RELAXED, __HIP_MEMORY_SCOPE_AGENT);
    verify8(v0, (const u64*)h0b, lane, dead);
    #pragma unroll
    for (int k = 0; k < 8; ++k) {
      const int i = k * 64 + lane;
      *(u64*)(smem + (i >> 3) * 80 + (i & 7) * 8) = v0[k];   // hs0[0]
    }
    asm volatile("s_waitcnt lgkmcnt(0)" ::: "memory");
    __hip_atomic_store(fstage0, 1u, __ATOMIC_RELEASE, __HIP_MEMORY_SCOPE_WORKGROUP);
  }
  // wave1: pre-issue h1[0] snapshot (init-ready), used at round 1
  if (wave == 1) {
    #pragma unroll
    for (int k = 0; k < 8; ++k)
      v1[k] = __hip_atomic_load((const u64*)h1b + k * 64 + lane, __ATOMIC_RELAXED, __HIP_MEMORY_SCOPE_AGENT);
  }

  for (int r = 0; r < ROUNDS; ++r) {
    const int par = r & 1;
    unsigned char* hs0p = smem + par * 5120;
    unsigned char* hs1p = smem + 10240 + par * 5120;

    const int rx = (r < SEQ) ? r : 0;
    const float x0v = xin[2 * rx];
    const float x1v = xin[2 * rx + 1];

    // ================= (1) L0 compute (all waves) =================
    lds_spin_ge(fstage0, (u32)(r + 1), dead);
    __builtin_amdgcn_sched_barrier(0);
    {
      float a0_[4] = {0.f, 0.f, 0.f, 0.f};
      #pragma unroll
      for (int c = 0; c < 4; ++c) {
        const uint4 u0v = *(const uint4*)(hs0p + lane * 80 + c * 16);
        #pragma unroll
        for (int m = 0; m < 4; ++m) {
          a0_[m] = dot2(wgt[m][0][4 * c + 0], u0v.x, a0_[m]);
          a0_[m] = dot2(wgt[m][0][4 * c + 1], u0v.y, a0_[m]);
          a0_[m] = dot2(wgt[m][0][4 * c + 2], u0v.z, a0_[m]);
          a0_[m] = dot2(wgt[m][0][4 * c + 3], u0v.w, a0_[m]);
        }
      }
      const float s0 = wave_reduce63(a0_[0]);
      const float s1 = wave_reduce63(a0_[1]);
      const float s2 = wave_reduce63(a0_[2]);
      const float s3 = wave_reduce63(a0_[3]);
      if (r < SEQ && lane == 63) {
        const float zi = s0 + bs0[0] + wx0[0] * x0v + wx1[0] * x1v;
        const float zf = s1 + bs0[1] + wx0[1] * x0v + wx1[1] * x1v;
        const float zg = s2 + bs0[2] + wx0[2] * x0v + wx1[2] * x1v;
        const float zo = s3 + bs0[3] + wx0[3] * x0v + wx1[3] * x1v;
        const float ig = sigm(zi), fg = sigm(zf), gg = tanh_(zg), og = sigm(zo);
        c0st = fg * c0st + ig * gg;
        const float hv = og * tanh_(c0st);
        const f16 hh = (f16)hv;
        hres0[par * 8 + wave] = (u32)__builtin_bit_cast(u16, hh);
        asm volatile("s_waitcnt lgkmcnt(0)" ::: "memory");
        __hip_atomic_store(&fgath0[wave], (u32)(r + 1), __ATOMIC_RELEASE, __HIP_MEMORY_SCOPE_WORKGROUP);
      }
    }

    // wave0: pre-issue v0 snapshot of h0[r+1] (publishes shortly; verified at (7))
    if (wave == 0 && r < SEQ) {
      #pragma unroll
      for (int k = 0; k < 8; ++k)
        v0[k] = __hip_atomic_load((const u64*)h0b + (size_t)(r + 1) * (H / 4) + k * 64 + lane,
                                  __ATOMIC_RELAXED, __HIP_MEMORY_SCOPE_AGENT);
    }

    // ================= (2) publish h0[r+1] (wave 2, lanes 0-1, one u64 each) ====
    if (wave == 2 && r < SEQ && lane < 2) {
      lds_spin8_ge(fgath0, (u32)(r + 1), dead);
      __builtin_amdgcn_sched_barrier(0);
      const u32* hr = hres0 + par * 8 + lane * 4;
      const u64 pv = (u64)(hr[0] & 0xffffu)
                   | ((u64)(hr[1] & 0xffffu) << 16)
                   | ((u64)(hr[2] & 0xffffu) << 32)
                   | ((u64)(hr[3] & 0xffffu) << 48);
      __hip_atomic_store((u64*)(h0b + (size_t)(r + 1) * H) + b * 2 + lane, pv,
                         __ATOMIC_RELAXED, __HIP_MEMORY_SCOPE_AGENT);
    }

    // ================= (3) stage h1[r-1] (wave 1) =================
    if (wave == 1 && r >= 1) {
      if (r >= 2) lds_spin8_ge(fdone, (u32)(r - 1), dead);   // hs1[par] reuse gate
      verify8(v1, (const u64*)h1b + (size_t)(r - 1) * (H / 4), lane, dead);
      #pragma unroll
      for (int k = 0; k < 8; ++k) {
        const int i = k * 64 + lane;
        *(u64*)(hs1p + (i >> 3) * 80 + (i & 7) * 8) = v1[k];
      }
      asm volatile("s_waitcnt lgkmcnt(0)" ::: "memory");
      __hip_atomic_store(fstage1, (u32)(r + 1), __ATOMIC_RELEASE, __HIP_MEMORY_SCOPE_WORKGROUP);
    }

    // ================= (4) L1 compute (all waves, r>=1) =================
    if (r >= 1) {
      lds_spin_ge(fstage1, (u32)(r + 1), dead);
      __builtin_amdgcn_sched_barrier(0);
      float a1_[4] = {0.f, 0.f, 0.f, 0.f};
      #pragma unroll
      for (int c = 0; c < 4; ++c) {
        const uint4 u0v = *(const uint4*)(hs0p + lane * 80 + c * 16);
        const uint4 u1v = *(const uint4*)(hs1p + lane * 80 + c * 16);
        #pragma unroll
        for (int m = 0; m < 4; ++m) {
          a1_[m] = dot2(wgt[m][1][4 * c + 0], u0v.x, a1_[m]);
          a1_[m] = dot2(wgt[m][1][4 * c + 1], u0v.y, a1_[m]);
          a1_[m] = dot2(wgt[m][1][4 * c + 2], u0v.z, a1_[m]);
          a1_[m] = dot2(wgt[m][1][4 * c + 3], u0v.w, a1_[m]);
          a1_[m] = dot2(wgt[m][2][4 * c + 0], u1v.x, a1_[m]);
          a1_[m] = dot2(wgt[m][2][4 * c + 1], u1v.y, a1_[m]);
          a1_[m] = dot2(wgt[m][2][4 * c + 2], u1v.z, a1_[m]);
          a1_[m] = dot2(wgt[m][2][4 * c + 3], u1v.w, a1_[m]);
        }
      }
      const float s0 = wave_reduce63(a1_[0]);
      const float s1 = wave_reduce63(a1_[1]);
      const float s2 = wave_reduce63(a1_[2]);
      const float s3 = wave_reduce63(a1_[3]);
      if (lane == 63) {
        const float ig = sigm(s0 + bs1[0]);
        const float fg = sigm(s1 + bs1[1]);
        const float gg = tanh_(s2 + bs1[2]);
        const float og = sigm(s3 + bs1[3]);
        c1st = fg * c1st + ig * gg;
        const float hv = og * tanh_(c1st);
        const f16 hh = (f16)hv;
        hres1[par * 8 + wave] = (u32)__builtin_bit_cast(u16, hh);
        asm volatile("s_waitcnt lgkmcnt(0)" ::: "memory");
        __hip_atomic_store(&fgath1[wave], (u32)(r + 1), __ATOMIC_RELEASE, __HIP_MEMORY_SCOPE_WORKGROUP);
      }
    }

    // ================= (5) publish h1[r] (wave 3, lanes 0-1) =================
    if (wave == 3 && r >= 1 && lane < 2) {
      lds_spin8_ge(fgath1, (u32)(r + 1), dead);
      __builtin_amdgcn_sched_barrier(0);
      const u32* hr = hres1 + par * 8 + lane * 4;
      const u64 pv = (u64)(hr[0] & 0xffffu)
                   | ((u64)(hr[1] & 0xffffu) << 16)
                   | ((u64)(hr[2] & 0xffffu) << 32)
                   | ((u64)(hr[3] & 0xffffu) << 48);
      __hip_atomic_store((u64*)(h1b + (size_t)r * H) + b * 2 + lane, pv,
                         __ATOMIC_RELAXED, __HIP_MEMORY_SCOPE_AGENT);
    }

    // wave1: pre-issue v1 snapshot of h1[r] (publishes ~now; verified next round (3))
    if (wave == 1 && r < SEQ) {
      #pragma unroll
      for (int k = 0; k < 8; ++k)
        v1[k] = __hip_atomic_load((const u64*)h1b + (size_t)r * (H / 4) + k * 64 + lane,
                                  __ATOMIC_RELAXED, __HIP_MEMORY_SCOPE_AGENT);
    }

    // ================= (6) round complete =================
    __hip_atomic_store(&fdone[wave], (u32)(r + 1), __ATOMIC_RELEASE, __HIP_MEMORY_SCOPE_WORKGROUP);

    // ================= (7) wave0 EARLY-stage h0[r+1] for round r+1 ============
    if (wave == 0 && r < SEQ) {
      lds_spin8_ge(fdone, (u32)r, dead);       // hs0[(r+1)&1] reuse gate (round r-1 readers done)
      verify8(v0, (const u64*)h0b + (size_t)(r + 1) * (H / 4), lane, dead);
      unsigned char* hs0n = smem + ((r + 1) & 1) * 5120;
      #pragma unroll
      for (int k = 0; k < 8; ++k) {
        const int i = k * 64 + lane;
        *(u64*)(hs0n + (i >> 3) * 80 + (i & 7) * 8) = v0[k];
      }
      asm volatile("s_waitcnt lgkmcnt(0)" ::: "memory");
      __hip_atomic_store(fstage0, (u32)(r + 2), __ATOMIC_RELEASE, __HIP_MEMORY_SCOPE_WORKGROUP);
    }
  }
}

// ---------------- final linear: out = W_lin @ h1_SEQ + b_lin ----------------
__global__ void lstm_fin(const unsigned char* __restrict__ wsb,
                         const float* __restrict__ Wlin,   // [2,H]
                         const float* __restrict__ blin,   // [2]
                         float* __restrict__ out)
{
  __shared__ float red[2][4];
  const f16* h1 = (const f16*)(wsb + H1_OFF) + (size_t)SEQ * H;
  const int tid = threadIdx.x;  // 256 threads
  float p0 = 0.f, p1 = 0.f;
  for (int k = tid; k < H; k += 256) {
    const float h = (float)h1[k];
    p0 += h * Wlin[k];
    p1 += h * Wlin[H + k];
  }
  p0 = wave_reduce63(p0);
  p1 = wave_reduce63(p1);
  const int wv = tid >> 6, ln = tid & 63;
  if (ln == 63) { red[0][wv] = p0; red[1][wv] = p1; }
  __syncthreads();
  if (tid == 0) {
    out[0] = blin[0] + red[0][0] + red[0][1] + red[0][2] + red[0][3];
    out[1] = blin[1] + red[1][0] + red[1][1] + red[1][2] + red[1][3];
  }
}

extern "C" void kernel_launch(void* const* d_in, const int* in_sizes, int n_in,
                              void* d_out, int out_size, void* d_ws, size_t ws_size,
                              hipStream_t stream) {
  const float* xin  = (const float*)d_in[0];
  const float* h0in = (const float*)d_in[1];
  const float* c0in = (const float*)d_in[2];
  const float* Wih0 = (const float*)d_in[3];
  const float* Whh0 = (const float*)d_in[4];
  const float* bih0 = (const float*)d_in[5];
  const float* bhh0 = (const float*)d_in[6];
  const float* Wih1 = (const float*)d_in[7];
  const float* Whh1 = (const float*)d_in[8];
  const float* bih1 = (const float*)d_in[9];
  const float* bhh1 = (const float*)d_in[10];
  const float* Wlin = (const float*)d_in[11];
  const float* blin = (const float*)d_in[12];
  unsigned char* wsb = (unsigned char*)d_ws;

  if (ws_size < WS_NEED) return;  // fail visibly (output stays poisoned)

  lstm_init<<<dim3((PER_BUF_U32 + 255) / 256), dim3(256), 0, stream>>>(h0in, wsb);
  lstm_pers<<<dim3(NB), dim3(NT), 0, stream>>>(xin, c0in, Wih0, Whh0, bih0, bhh0,
                                               Wih1, Whh1, bih1, bhh1, wsb);
  lstm_fin<<<dim3(1), dim3(256), 0, stream>>>(wsb, Wlin, blin, (float*)d_out);
}

// Round 14
// 4849.653 us; speedup vs baseline: 1.8750x; 1.8750x over previous
//
#include <hip/hip_runtime.h>
#include <stdint.h>

// ---------------- problem constants ----------------
#define H      2048
#define SEQ    1024
#define NB     256      // persistent blocks (1 per CU)
#define NT     512      // threads per block (8 waves)
#define JPB    8        // hidden units per block per layer (H / NB)
#define ROUNDS (SEQ + 1)
#define LIMG   (1 << 11)   // global-spin bail (~1ms; each iter ~ a load latency)
#define LIML   (1 << 15)   // LDS-spin bail

typedef _Float16 f16;
typedef _Float16 f16x2 __attribute__((ext_vector_type(2)));
typedef unsigned int u32;
typedef unsigned long long u64;
typedef unsigned short u16;

// ---------------- workspace layout (bytes) ----------------
static const size_t H0_OFF  = 4096;
static const size_t HBYTES  = (size_t)(SEQ + 2) * H * 2;   // 4,202,496
static const size_t H1_OFF  = H0_OFF + HBYTES;
static const size_t WS_NEED = H1_OFF + HBYTES;             // ~8.4 MB

// ---------------- LDS layout (bytes) ----------------
//     0..10239 : hs0[2][5120]  (h0 stage, 80B-pad rows, dbuf r&1)
// 10240..20479 : hs1[2][5120]
// 20480..20543 : hres0[2][8] u32 ; 20544..20607 : hres1[2][8] u32
// 20608 fstage0 ; 20612 fstage1 ; 20616 fgath0[8] ; 20648 fgath1[8]
// 20680 fdone[8] ; 20712 dead
// 20736..21247 : ucst[8][16] f32 (per-wave cell constants)
#define UCST_OFF 20736
#define LDS_BYTES 21248

// ---------------- helpers ----------------
__device__ __forceinline__ u32 pk2(float a, float b) {
  f16x2 h; h.x = (f16)a; h.y = (f16)b;
  return __builtin_bit_cast(u32, h);
}

__device__ __forceinline__ float dot2(u32 a, u32 b, float c) {
#if __has_builtin(__builtin_amdgcn_fdot2)
  return __builtin_amdgcn_fdot2(__builtin_bit_cast(f16x2, a),
                                __builtin_bit_cast(f16x2, b), c, false);
#else
  f16x2 av = __builtin_bit_cast(f16x2, a);
  f16x2 bv = __builtin_bit_cast(f16x2, b);
  return c + (float)av.x * (float)bv.x + (float)av.y * (float)bv.y;
#endif
}

template <int CTRL>
__device__ __forceinline__ float dppadd(float x) {
  int y = __builtin_amdgcn_update_dpp(0, __float_as_int(x), CTRL, 0xF, 0xF, false);
  return x + __int_as_float(y);
}
__device__ __forceinline__ float wave_reduce63(float x) {
  x = dppadd<0x111>(x); x = dppadd<0x112>(x); x = dppadd<0x114>(x);
  x = dppadd<0x118>(x); x = dppadd<0x142>(x); x = dppadd<0x143>(x);
  return x;   // total in lane 63
}

__device__ __forceinline__ float sigm(float x) { return 1.0f / (1.0f + __expf(-x)); }
__device__ __forceinline__ float tanh_(float x) {
  float t = __expf(-2.0f * fabsf(x));
  float r = (1.0f - t) / (1.0f + t);
  return copysignf(r, x);
}

// any u16 half equals 0x7C00 (f16 +inf sentinel)? produced |h|<1 -> never 0x7C00
__device__ __forceinline__ bool has_sent(u64 v) {
  const u64 x = v ^ 0x7C007C007C007C00ull;
  return ((x - 0x0001000100010001ull) & ~x & 0x8000800080008000ull) != 0ull;
}

// verify 8 pre-issued u64 snapshots of one h row-slice; reload stale lanes
__device__ __forceinline__ void verify8(u64 v[8], const u64* base, int lane, u32* dead) {
  int it = 0;
  while (true) {
    bool all = true;
    #pragma unroll
    for (int k = 0; k < 8; ++k)
      if (has_sent(v[k])) {
        all = false;
        v[k] = __hip_atomic_load(base + k * 64 + lane, __ATOMIC_RELAXED, __HIP_MEMORY_SCOPE_AGENT);
      }
    if (all) break;
    if (*(volatile u32*)dead) break;
    if (++it > LIMG) { *(volatile u32*)dead = 1; break; }
    __builtin_amdgcn_s_sleep(1);
  }
}

__device__ __forceinline__ void lds_spin_ge(u32* f, u32 val, u32* dead) {
  int it = 0;
  while (__hip_atomic_load(f, __ATOMIC_ACQUIRE, __HIP_MEMORY_SCOPE_WORKGROUP) < val) {
    if (*(volatile u32*)dead) break;
    if (++it > LIML) { *(volatile u32*)dead = 1; break; }
  }
}
__device__ __forceinline__ void lds_spin8_ge(u32* f, u32 val, u32* dead) {
  int it = 0;
  while (true) {
    bool ok = true;
    #pragma unroll
    for (int w = 0; w < 8; ++w)
      ok &= (__hip_atomic_load(f + w, __ATOMIC_ACQUIRE, __HIP_MEMORY_SCOPE_WORKGROUP) >= val);
    if (ok) break;
    if (*(volatile u32*)dead) break;
    if (++it > LIML) { *(volatile u32*)dead = 1; break; }
  }
}

// ---------------- init kernel: sentinel-fill h buffers, write initial states ----------------
#define PER_BUF_U32 ((SEQ + 1) * (H / 2))
__global__ void lstm_init(const float* __restrict__ h0in, unsigned char* __restrict__ wsb) {
  const int i = blockIdx.x * blockDim.x + threadIdx.x;
  u32* b0 = (u32*)(wsb + H0_OFF);
  u32* b1 = (u32*)(wsb + H1_OFF);
  if (i < H / 2) {
    b0[i] = pk2(h0in[2 * i], h0in[2 * i + 1]);
    b1[i] = pk2(h0in[H + 2 * i], h0in[H + 2 * i + 1]);
  } else if (i < PER_BUF_U32) {
    b0[i] = 0x7C007C00u;
    b1[i] = 0x7C007C00u;
  }
}

// ---------------- persistent LSTM: wave-autonomous, zero in-loop barriers ----------------
// Round r per wave: L0 compute -> [w2: publish h0[r+1]] -> [w1: stage h1[r-1]]
// -> L1 compute -> [w3: publish h1[r]] -> fdone -> [w0: EARLY-stage h0[r+1]].
// fstage0 for round r+1 is set during round r, so L0 starts with zero detect.
// Register diet vs r13: single shared vsnap[8] (w0:h0 / w1:h1) + cell constants
// in LDS -> wgt[192] fits the 256-reg budget again (r13 spilled: WRITE 139MB).
__global__ __launch_bounds__(NT, 1) void lstm_pers(
    const float* __restrict__ xin,   // [SEQ,2]
    const float* __restrict__ c0in,  // [2,1,H]
    const float* __restrict__ Wih0,  // [4H,2]
    const float* __restrict__ Whh0,  // [4H,H]
    const float* __restrict__ bih0,
    const float* __restrict__ bhh0,
    const float* __restrict__ Wih1,  // [4H,H]
    const float* __restrict__ Whh1,  // [4H,H]
    const float* __restrict__ bih1,
    const float* __restrict__ bhh1,
    unsigned char* __restrict__ wsb)
{
  const int b    = blockIdx.x;
  const int tid  = threadIdx.x;
  const int lane = tid & 63;
  const int wave = tid >> 6;

  f16* h0b = (f16*)(wsb + H0_OFF);
  f16* h1b = (f16*)(wsb + H1_OFF);

  __shared__ __align__(16) unsigned char smem[LDS_BYTES];
  u32* hres0   = (u32*)(smem + 20480);   // [2][8]
  u32* hres1   = (u32*)(smem + 20544);   // [2][8]
  u32* fstage0 = (u32*)(smem + 20608);
  u32* fstage1 = (u32*)(smem + 20612);
  u32* fgath0  = (u32*)(smem + 20616);   // [8]
  u32* fgath1  = (u32*)(smem + 20648);   // [8]
  u32* fdone   = (u32*)(smem + 20680);   // [8]
  u32* dead    = (u32*)(smem + 20712);
  float* ucst  = (float*)(smem + UCST_OFF);   // [8][16]

  if (tid < 32) ((u32*)(smem + 20608))[tid] = 0;   // zero flags + dead

  // per-wave cell constants -> LDS: q0-3 Wih0 col0, q4-7 col1, q8-11 bsum0, q12-15 bsum1
  if (tid < 128) {
    const int w = tid >> 4, q = tid & 15, m = q & 3;
    const int R = m * H + b * JPB + w;
    float v;
    if (q < 4)       v = Wih0[(size_t)R * 2 + 0];
    else if (q < 8)  v = Wih0[(size_t)R * 2 + 1];
    else if (q < 12) v = bih0[R] + bhh0[R];
    else             v = bih1[R] + bhh1[R];
    ucst[w * 16 + q] = v;
  }

  const int u = b * JPB + wave;
  float c0st = c0in[u];
  float c1st = c0in[H + u];

  // ---- weights: wave owns unit u for all 3 matrices (12 rows, 192 u32) ----
  u32 wgt[4][3][16];
  {
    #pragma unroll
    for (int m = 0; m < 4; ++m) {
      const int R = m * H + u;
      const float* srcs[3] = { Whh0 + (size_t)R * H, Wih1 + (size_t)R * H, Whh1 + (size_t)R * H };
      #pragma unroll
      for (int mat = 0; mat < 3; ++mat) {
        const float4* s4 = (const float4*)(srcs[mat] + lane * 32);
        #pragma unroll
        for (int i = 0; i < 8; ++i) {
          float4 f = s4[i];
          wgt[m][mat][2 * i]     = pk2(f.x, f.y);
          wgt[m][mat][2 * i + 1] = pk2(f.z, f.w);
        }
        __builtin_amdgcn_sched_barrier(0);
      }
    }
  }
  __syncthreads();   // startup only: flags+consts in LDS, weights loaded

  // shared snapshot array: wave0 -> h0 rows, wave1 -> h1 rows (never both)
  u64 vsnap[8];
  if (wave == 0) {
    #pragma unroll
    for (int k = 0; k < 8; ++k)
      vsnap[k] = __hip_atomic_load((const u64*)h0b + k * 64 + lane, __ATOMIC_RELAXED, __HIP_MEMORY_SCOPE_AGENT);
    verify8(vsnap, (const u64*)h0b, lane, dead);
    #pragma unroll
    for (int k = 0; k < 8; ++k) {
      const int i = k * 64 + lane;
      *(u64*)(smem + (i >> 3) * 80 + (i & 7) * 8) = vsnap[k];   // hs0[0]
    }
    asm volatile("s_waitcnt lgkmcnt(0)" ::: "memory");
    __hip_atomic_store(fstage0, 1u, __ATOMIC_RELEASE, __HIP_MEMORY_SCOPE_WORKGROUP);
  }
  if (wave == 1) {
    #pragma unroll
    for (int k = 0; k < 8; ++k)
      vsnap[k] = __hip_atomic_load((const u64*)h1b + k * 64 + lane, __ATOMIC_RELAXED, __HIP_MEMORY_SCOPE_AGENT);
  }

  for (int r = 0; r < ROUNDS; ++r) {
    const int par = r & 1;
    unsigned char* hs0p = smem + par * 5120;
    unsigned char* hs1p = smem + 10240 + par * 5120;

    const int rx = (r < SEQ) ? r : 0;
    const float x0v = xin[2 * rx];
    const float x1v = xin[2 * rx + 1];

    // ================= (1) L0 compute (all waves) =================
    lds_spin_ge(fstage0, (u32)(r + 1), dead);
    __builtin_amdgcn_sched_barrier(0);
    {
      float a0_[4] = {0.f, 0.f, 0.f, 0.f};
      #pragma unroll
      for (int c = 0; c < 4; ++c) {
        const uint4 u0v = *(const uint4*)(hs0p + lane * 80 + c * 16);
        #pragma unroll
        for (int m = 0; m < 4; ++m) {
          a0_[m] = dot2(wgt[m][0][4 * c + 0], u0v.x, a0_[m]);
          a0_[m] = dot2(wgt[m][0][4 * c + 1], u0v.y, a0_[m]);
          a0_[m] = dot2(wgt[m][0][4 * c + 2], u0v.z, a0_[m]);
          a0_[m] = dot2(wgt[m][0][4 * c + 3], u0v.w, a0_[m]);
        }
      }
      const float s0 = wave_reduce63(a0_[0]);
      const float s1 = wave_reduce63(a0_[1]);
      const float s2 = wave_reduce63(a0_[2]);
      const float s3 = wave_reduce63(a0_[3]);
      if (r < SEQ && lane == 63) {
        const float* uc = ucst + wave * 16;
        const float zi = s0 + uc[8]  + uc[0] * x0v + uc[4] * x1v;
        const float zf = s1 + uc[9]  + uc[1] * x0v + uc[5] * x1v;
        const float zg = s2 + uc[10] + uc[2] * x0v + uc[6] * x1v;
        const float zo = s3 + uc[11] + uc[3] * x0v + uc[7] * x1v;
        const float ig = sigm(zi), fg = sigm(zf), gg = tanh_(zg), og = sigm(zo);
        c0st = fg * c0st + ig * gg;
        const float hv = og * tanh_(c0st);
        const f16 hh = (f16)hv;
        hres0[par * 8 + wave] = (u32)__builtin_bit_cast(u16, hh);
        asm volatile("s_waitcnt lgkmcnt(0)" ::: "memory");
        __hip_atomic_store(&fgath0[wave], (u32)(r + 1), __ATOMIC_RELEASE, __HIP_MEMORY_SCOPE_WORKGROUP);
      }
    }

    // wave0: pre-issue vsnap of h0[r+1] (publishes shortly; verified at (7))
    if (wave == 0 && r < SEQ) {
      #pragma unroll
      for (int k = 0; k < 8; ++k)
        vsnap[k] = __hip_atomic_load((const u64*)h0b + (size_t)(r + 1) * (H / 4) + k * 64 + lane,
                                     __ATOMIC_RELAXED, __HIP_MEMORY_SCOPE_AGENT);
    }

    // ================= (2) publish h0[r+1] (wave 2, lanes 0-1, one u64 each) ====
    if (wave == 2 && r < SEQ && lane < 2) {
      lds_spin8_ge(fgath0, (u32)(r + 1), dead);
      __builtin_amdgcn_sched_barrier(0);
      const u32* hr = hres0 + par * 8 + lane * 4;
      const u64 pv = (u64)(hr[0] & 0xffffu)
                   | ((u64)(hr[1] & 0xffffu) << 16)
                   | ((u64)(hr[2] & 0xffffu) << 32)
                   | ((u64)(hr[3] & 0xffffu) << 48);
      __hip_atomic_store((u64*)(h0b + (size_t)(r + 1) * H) + b * 2 + lane, pv,
                         __ATOMIC_RELAXED, __HIP_MEMORY_SCOPE_AGENT);
    }

    // ================= (3) stage h1[r-1] (wave 1) =================
    if (wave == 1 && r >= 1) {
      if (r >= 2) lds_spin8_ge(fdone, (u32)(r - 1), dead);   // hs1[par] reuse gate
      verify8(vsnap, (const u64*)h1b + (size_t)(r - 1) * (H / 4), lane, dead);
      #pragma unroll
      for (int k = 0; k < 8; ++k) {
        const int i = k * 64 + lane;
        *(u64*)(hs1p + (i >> 3) * 80 + (i & 7) * 8) = vsnap[k];
      }
      asm volatile("s_waitcnt lgkmcnt(0)" ::: "memory");
      __hip_atomic_store(fstage1, (u32)(r + 1), __ATOMIC_RELEASE, __HIP_MEMORY_SCOPE_WORKGROUP);
    }

    // ================= (4) L1 compute (all waves, r>=1) =================
    if (r >= 1) {
      lds_spin_ge(fstage1, (u32)(r + 1), dead);
      __builtin_amdgcn_sched_barrier(0);
      float a1_[4] = {0.f, 0.f, 0.f, 0.f};
      #pragma unroll
      for (int c = 0; c < 4; ++c) {
        const uint4 u0v = *(const uint4*)(hs0p + lane * 80 + c * 16);
        const uint4 u1v = *(const uint4*)(hs1p + lane * 80 + c * 16);
        #pragma unroll
        for (int m = 0; m < 4; ++m) {
          a1_[m] = dot2(wgt[m][1][4 * c + 0], u0v.x, a1_[m]);
          a1_[m] = dot2(wgt[m][1][4 * c + 1], u0v.y, a1_[m]);
          a1_[m] = dot2(wgt[m][1][4 * c + 2], u0v.z, a1_[m]);
          a1_[m] = dot2(wgt[m][1][4 * c + 3], u0v.w, a1_[m]);
          a1_[m] = dot2(wgt[m][2][4 * c + 0], u1v.x, a1_[m]);
          a1_[m] = dot2(wgt[m][2][4 * c + 1], u1v.y, a1_[m]);
          a1_[m] = dot2(wgt[m][2][4 * c + 2], u1v.z, a1_[m]);
          a1_[m] = dot2(wgt[m][2][4 * c + 3], u1v.w, a1_[m]);
        }
      }
      const float s0 = wave_reduce63(a1_[0]);
      const float s1 = wave_reduce63(a1_[1]);
      const float s2 = wave_reduce63(a1_[2]);
      const float s3 = wave_reduce63(a1_[3]);
      if (lane == 63) {
        const float* uc = ucst + wave * 16;
        const float ig = sigm(s0 + uc[12]);
        const float fg = sigm(s1 + uc[13]);
        const float gg = tanh_(s2 + uc[14]);
        const float og = sigm(s3 + uc[15]);
        c1st = fg * c1st + ig * gg;
        const float hv = og * tanh_(c1st);
        const f16 hh = (f16)hv;
        hres1[par * 8 + wave] = (u32)__builtin_bit_cast(u16, hh);
        asm volatile("s_waitcnt lgkmcnt(0)" ::: "memory");
        __hip_atomic_store(&fgath1[wave], (u32)(r + 1), __ATOMIC_RELEASE, __HIP_MEMORY_SCOPE_WORKGROUP);
      }
    }

    // ================= (5) publish h1[r] (wave 3, lanes 0-1) =================
    if (wave == 3 && r >= 1 && lane < 2) {
      lds_spin8_ge(fgath1, (u32)(r + 1), dead);
      __builtin_amdgcn_sched_barrier(0);
      const u32* hr = hres1 + par * 8 + lane * 4;
      const u64 pv = (u64)(hr[0] & 0xffffu)
                   | ((u64)(hr[1] & 0xffffu) << 16)
                   | ((u64)(hr[2] & 0xffffu) << 32)
                   | ((u64)(hr[3] & 0xffffu) << 48);
      __hip_atomic_store((u64*)(h1b + (size_t)r * H) + b * 2 + lane, pv,
                         __ATOMIC_RELAXED, __HIP_MEMORY_SCOPE_AGENT);
    }

    // wave1: pre-issue vsnap of h1[r] (publishes ~now; verified next round (3))
    if (wave == 1 && r < SEQ) {
      #pragma unroll
      for (int k = 0; k < 8; ++k)
        vsnap[k] = __hip_atomic_load((const u64*)h1b + (size_t)r * (H / 4) + k * 64 + lane,
                                     __ATOMIC_RELAXED, __HIP_MEMORY_SCOPE_AGENT);
    }

    // ================= (6) round complete =================
    __hip_atomic_store(&fdone[wave], (u32)(r + 1), __ATOMIC_RELEASE, __HIP_MEMORY_SCOPE_WORKGROUP);

    // ================= (7) wave0 EARLY-stage h0[r+1] for round r+1 ============
    if (wave == 0 && r < SEQ) {
      lds_spin8_ge(fdone, (u32)r, dead);       // hs0[(r+1)&1] reuse gate
      verify8(vsnap, (const u64*)h0b + (size_t)(r + 1) * (H / 4), lane, dead);
      unsigned char* hs0n = smem + ((r + 1) & 1) * 5120;
      #pragma unroll
      for (int k = 0; k < 8; ++k) {
        const int i = k * 64 + lane;
        *(u64*)(hs0n + (i >> 3) * 80 + (i & 7) * 8) = vsnap[k];
      }
      asm volatile("s_waitcnt lgkmcnt(0)" ::: "memory");
      __hip_atomic_store(fstage0, (u32)(r + 2), __ATOMIC_RELEASE, __HIP_MEMORY_SCOPE_WORKGROUP);
    }
  }
}

// ---------------- final linear: out = W_lin @ h1_SEQ + b_lin ----------------
__global__ void lstm_fin(const unsigned char* __restrict__ wsb,
                         const float* __restrict__ Wlin,   // [2,H]
                         const float* __restrict__ blin,   // [2]
                         float* __restrict__ out)
{
  __shared__ float red[2][4];
  const f16* h1 = (const f16*)(wsb + H1_OFF) + (size_t)SEQ * H;
  const int tid = threadIdx.x;  // 256 threads
  float p0 = 0.f, p1 = 0.f;
  for (int k = tid; k < H; k += 256) {
    const float h = (float)h1[k];
    p0 += h * Wlin[k];
    p1 += h * Wlin[H + k];
  }
  p0 = wave_reduce63(p0);
  p1 = wave_reduce63(p1);
  const int wv = tid >> 6, ln = tid & 63;
  if (ln == 63) { red[0][wv] = p0; red[1][wv] = p1; }
  __syncthreads();
  if (tid == 0) {
    out[0] = blin[0] + red[0][0] + red[0][1] + red[0][2] + red[0][3];
    out[1] = blin[1] + red[1][0] + red[1][1] + red[1][2] + red[1][3];
  }
}

extern "C" void kernel_launch(void* const* d_in, const int* in_sizes, int n_in,
                              void* d_out, int out_size, void* d_ws, size_t ws_size,
                              hipStream_t stream) {
  const float* xin  = (const float*)d_in[0];
  const float* h0in = (const float*)d_in[1];
  const float* c0in = (const float*)d_in[2];
  const float* Wih0 = (const float*)d_in[3];
  const float* Whh0 = (const float*)d_in[4];
  const float* bih0 = (const float*)d_in[5];
  const float* bhh0 = (const float*)d_in[6];
  const float* Wih1 = (const float*)d_in[7];
  const float* Whh1 = (const float*)d_in[8];
  const float* bih1 = (const float*)d_in[9];
  const float* bhh1 = (const float*)d_in[10];
  const float* Wlin = (const float*)d_in[11];
  const float* blin = (const float*)d_in[12];
  unsigned char* wsb = (unsigned char*)d_ws;

  if (ws_size < WS_NEED) return;  // fail visibly (output stays poisoned)

  lstm_init<<<dim3((PER_BUF_U32 + 255) / 256), dim3(256), 0, stream>>>(h0in, wsb);
  lstm_pers<<<dim3(NB), dim3(NT), 0, stream>>>(xin, c0in, Wih0, Whh0, bih0, bhh0,
                                               Wih1, Whh1, bih1, bhh1, wsb);
  lstm_fin<<<dim3(1), dim3(256), 0, stream>>>(wsb, Wlin, blin, (float*)d_out);
}

// Round 15
// 3097.592 us; speedup vs baseline: 2.9355x; 1.5656x over previous
//
#include <hip/hip_runtime.h>
#include <stdint.h>

// ---------------- problem constants ----------------
#define H      2048
#define SEQ    1024
#define NB     256      // persistent blocks (1 per CU)
#define NT     512      // threads per block (8 waves)
#define JPB    8        // hidden units per block per layer (H / NB)
#define ROUNDS (SEQ + 1)

typedef _Float16 f16;
typedef _Float16 f16x2 __attribute__((ext_vector_type(2)));
typedef unsigned int u32;
typedef unsigned long long u64;
typedef unsigned short u16;

// ---------------- workspace layout (bytes) ----------------
static const size_t H0_OFF  = 4096;
static const size_t HBYTES  = (size_t)(SEQ + 2) * H * 2;   // 4,202,496
static const size_t H1_OFF  = H0_OFF + HBYTES;
static const size_t WS_NEED = H1_OFF + HBYTES;             // ~8.4 MB

// ---------------- helpers ----------------
__device__ __forceinline__ u32 pk2(float a, float b) {
  f16x2 h;
  h.x = (f16)a;  // RNE
  h.y = (f16)b;
  return __builtin_bit_cast(u32, h);
}

__device__ __forceinline__ float dot2(u32 a, u32 b, float c) {
#if __has_builtin(__builtin_amdgcn_fdot2)
  return __builtin_amdgcn_fdot2(__builtin_bit_cast(f16x2, a),
                                __builtin_bit_cast(f16x2, b), c, false);
#else
  f16x2 av = __builtin_bit_cast(f16x2, a);
  f16x2 bv = __builtin_bit_cast(f16x2, b);
  return c + (float)av.x * (float)bv.x + (float)av.y * (float)bv.y;
#endif
}

template <int CTRL>
__device__ __forceinline__ float dppadd(float x) {
  int y = __builtin_amdgcn_update_dpp(0, __float_as_int(x), CTRL, 0xF, 0xF, false);
  return x + __int_as_float(y);
}
// full 64-lane sum, valid in lane 63
__device__ __forceinline__ float wave_reduce63(float x) {
  x = dppadd<0x111>(x);  // row_shr:1
  x = dppadd<0x112>(x);  // row_shr:2
  x = dppadd<0x114>(x);  // row_shr:4
  x = dppadd<0x118>(x);  // row_shr:8
  x = dppadd<0x142>(x);  // row_bcast:15
  x = dppadd<0x143>(x);  // row_bcast:31 -> lane 63 has total
  return x;
}

__device__ __forceinline__ float sigm(float x) {
  return 1.0f / (1.0f + __expf(-x));
}
__device__ __forceinline__ float tanh_(float x) {
  float t = __expf(-2.0f * fabsf(x));       // in (0,1] — overflow-safe
  float r = (1.0f - t) / (1.0f + t);
  return copysignf(r, x);
}

// any 16-bit half equals 0x7C00 (f16 +inf sentinel)?  exact existence test
// (produced h always has |h|<1 -> exponent<15 -> never 0x7C00)
__device__ __forceinline__ bool has_sent(u64 v) {
  const u64 x = v ^ 0x7C007C007C007C00ull;
  return ((x - 0x0001000100010001ull) & ~x & 0x8000800080008000ull) != 0ull;
}

// LDS-only block barrier: lgkmcnt(0) + s_barrier, NO vmcnt drain.
// __syncthreads would emit s_waitcnt vmcnt(0) before s_barrier, absorbing the
// full flight of every in-flight global prefetch into the barrier. In-flight
// global loads here are per-lane register values validated by sentinel checks —
// no cross-wave ordering needed.
__device__ __forceinline__ void sync_lds() {
  __builtin_amdgcn_sched_barrier(0);
  asm volatile("s_waitcnt lgkmcnt(0)" ::: "memory");
  __builtin_amdgcn_s_barrier();
  __builtin_amdgcn_sched_barrier(0);
}

// ---------------- init kernel: sentinel-fill h buffers, write initial states ----------------
// Must run every call (harness only poisons once; replays need fresh sentinels).
#define PER_BUF_U32 ((SEQ + 1) * (H / 2))   // u32 words per buffer, rows 0..SEQ
__global__ void lstm_init(const float* __restrict__ h0in, unsigned char* __restrict__ wsb) {
  const int i = blockIdx.x * blockDim.x + threadIdx.x;
  u32* b0 = (u32*)(wsb + H0_OFF);
  u32* b1 = (u32*)(wsb + H1_OFF);
  if (i < H / 2) {
    // row 0 = initial hidden states (h0in layout: [2,1,H])
    b0[i] = pk2(h0in[2 * i], h0in[2 * i + 1]);
    b1[i] = pk2(h0in[H + 2 * i], h0in[H + 2 * i + 1]);
  } else if (i < PER_BUF_U32) {
    b0[i] = 0x7C007C00u;
    b1[i] = 0x7C007C00u;
  }
}

// ---------------- persistent LSTM kernel ----------------
// Round r (r = 0..SEQ), lockstep two-phase with pipelined polls and
// non-draining barriers (the empirical optimum of rounds 2-14):
//   verify v0 (= h0[r], pre-issued mid-prev-round; flew across syncC) -> stage
//   issue v1 load (h1[r-1]) -> syncA          (v1 keeps flying across syncA)
//   phase A (Whh0 dots) -> z0 ; verify v1 -> stage hs1 -> syncB
//   L0 combine + publish h0[r+1] ; pre-issue v0 for h0[r+1]
//   phase B (Wih1,Whh1 dots) -> z1 -> syncC   (v0 keeps flying across syncC)
//   L1 combine + publish h1[r]
__global__ __launch_bounds__(NT, 1) void lstm_pers(
    const float* __restrict__ xin,   // [SEQ,2]
    const float* __restrict__ c0in,  // [2,1,H]
    const float* __restrict__ Wih0,  // [4H,2]
    const float* __restrict__ Whh0,  // [4H,H]
    const float* __restrict__ bih0,
    const float* __restrict__ bhh0,
    const float* __restrict__ Wih1,  // [4H,H]
    const float* __restrict__ Whh1,  // [4H,H]
    const float* __restrict__ bih1,
    const float* __restrict__ bhh1,
    unsigned char* __restrict__ wsb)
{
  const int b    = blockIdx.x;
  const int tid  = threadIdx.x;
  const int lane = tid & 63;
  const int wave = tid >> 6;

  f16* h0b = (f16*)(wsb + H0_OFF);
  f16* h1b = (f16*)(wsb + H1_OFF);

  // LDS: double-buffered padded-row h stages (64 rows x 80B) + z slots
  __shared__ __align__(16) unsigned char smem[4 * 5120 + 256];
  float* z0buf = (float*)(smem + 20480);        // 32 floats
  float* z1buf = (float*)(smem + 20480 + 128);  // 32 floats

  // ---- combine-thread state in REGISTERS (tid<8: L0 unit tid; tid 8..15: L1 unit tid-8)
  float wx0q0 = 0.f, wx0q1 = 0.f, wx0q2 = 0.f, wx0q3 = 0.f;  // Wih0 col0 per gate
  float wx1q0 = 0.f, wx1q1 = 0.f, wx1q2 = 0.f, wx1q3 = 0.f;  // Wih0 col1 per gate
  float bsq0 = 0.f, bsq1 = 0.f, bsq2 = 0.f, bsq3 = 0.f;      // bih+bhh per gate
  float cst = 0.f;                                           // cell state
  if (tid < 8) {
    const int u = b * JPB + tid;
    wx0q0 = Wih0[(size_t)(0 * H + u) * 2];  wx1q0 = Wih0[(size_t)(0 * H + u) * 2 + 1];
    wx0q1 = Wih0[(size_t)(1 * H + u) * 2];  wx1q1 = Wih0[(size_t)(1 * H + u) * 2 + 1];
    wx0q2 = Wih0[(size_t)(2 * H + u) * 2];  wx1q2 = Wih0[(size_t)(2 * H + u) * 2 + 1];
    wx0q3 = Wih0[(size_t)(3 * H + u) * 2];  wx1q3 = Wih0[(size_t)(3 * H + u) * 2 + 1];
    bsq0 = bih0[0 * H + u] + bhh0[0 * H + u];
    bsq1 = bih0[1 * H + u] + bhh0[1 * H + u];
    bsq2 = bih0[2 * H + u] + bhh0[2 * H + u];
    bsq3 = bih0[3 * H + u] + bhh0[3 * H + u];
    cst  = c0in[u];
  } else if (tid < 16) {
    const int u = b * JPB + (tid - 8);
    bsq0 = bih1[0 * H + u] + bhh1[0 * H + u];
    bsq1 = bih1[1 * H + u] + bhh1[1 * H + u];
    bsq2 = bih1[2 * H + u] + bhh1[2 * H + u];
    bsq3 = bih1[3 * H + u] + bhh1[3 * H + u];
    cst  = c0in[H + u];
  }

  // ---- load weights into registers as packed f16 pairs ----
  // wave w owns unit (b*8 + w); rows m*H + b*8 + w for gates m=0..3 (i,f,g,o)
  // lane covers k = lane*32 .. lane*32+31 (16 f16 pairs per row per matrix)
  u32 wgt[4][3][16];
  {
    #pragma unroll
    for (int m = 0; m < 4; ++m) {
      const int R = m * H + b * JPB + wave;
      const float* srcs[3] = { Whh0 + (size_t)R * H, Wih1 + (size_t)R * H, Whh1 + (size_t)R * H };
      #pragma unroll
      for (int mat = 0; mat < 3; ++mat) {
        const float4* s4 = (const float4*)(srcs[mat] + lane * 32);
        #pragma unroll
        for (int i = 0; i < 8; ++i) {
          float4 f = s4[i];
          wgt[m][mat][2 * i]     = pk2(f.x, f.y);
          wgt[m][mat][2 * i + 1] = pk2(f.z, f.w);
        }
        __builtin_amdgcn_sched_barrier(0);  // cap transient register pressure
      }
    }
  }
  __syncthreads();   // once, pre-loop: full drain is fine here

  const int row = tid >> 3, q = tid & 7;       // LDS write slot (80B row pitch)
  const int wba = row * 80 + q * 8;

  // pre-issue the first h0 poll load (row 0: ready from init)
  u64 v0 = __hip_atomic_load((const u64*)h0b + tid, __ATOMIC_RELAXED, __HIP_MEMORY_SCOPE_AGENT);

  for (int r = 0; r < ROUNDS; ++r) {
    const int rp  = (r > 0) ? (r - 1) : 0;
    const int buf = (r & 1) * 5120;
    unsigned char* hs0 = smem + buf;
    unsigned char* hs1 = smem + 10240 + buf;

    // x for this round (uniform scalar loads, off critical path)
    const int rx = (r < SEQ) ? r : 0;
    const float x0v = xin[2 * rx];
    const float x1v = xin[2 * rx + 1];

    // ---- verify pre-issued v0 = h0[r] (steady state: register check, no LLC) ----
    {
      const u64* s0p = (const u64*)h0b + (size_t)r * (H / 4) + tid;
      int it = 0;
      while (has_sent(v0)) {
        if (++it > (1 << 18)) break;           // hang-safety
        __builtin_amdgcn_s_sleep(1);
        v0 = __hip_atomic_load(s0p, __ATOMIC_RELAXED, __HIP_MEMORY_SCOPE_AGENT);
      }
      *(u64*)(hs0 + wba) = v0;
    }

    // issue h1[r-1] load; flies across syncA + phase A before its verify
    const u64* s1p = (const u64*)h1b + (size_t)rp * (H / 4) + tid;
    u64 v1 = __hip_atomic_load(s1p, __ATOMIC_RELAXED, __HIP_MEMORY_SCOPE_AGENT);

    sync_lds();                                // sync A: hs0 staged (no vmcnt drain)

    // ---- phase A: z0 = Whh0 · h0_r (64 dot2/lane) ----
    float a0[4] = {0.f, 0.f, 0.f, 0.f};
    #pragma unroll
    for (int c = 0; c < 4; ++c) {
      const uint4 u0 = *(const uint4*)(hs0 + lane * 80 + c * 16);
      #pragma unroll
      for (int m = 0; m < 4; ++m) {
        a0[m] = dot2(wgt[m][0][4 * c + 0], u0.x, a0[m]);
        a0[m] = dot2(wgt[m][0][4 * c + 1], u0.y, a0[m]);
        a0[m] = dot2(wgt[m][0][4 * c + 2], u0.z, a0[m]);
        a0[m] = dot2(wgt[m][0][4 * c + 3], u0.w, a0[m]);
      }
    }
    {
      const float s0 = wave_reduce63(a0[0]);
      const float s1 = wave_reduce63(a0[1]);
      const float s2 = wave_reduce63(a0[2]);
      const float s3 = wave_reduce63(a0[3]);
      if (lane == 63) {
        z0buf[4 * wave + 0] = s0;
        z0buf[4 * wave + 1] = s1;
        z0buf[4 * wave + 2] = s2;
        z0buf[4 * wave + 3] = s3;
      }
    }

    // ---- h1[r-1]: verify the early load (~0.5us of cover since issue) ----
    int it1 = 0;
    while (has_sent(v1)) {
      if (++it1 > (1 << 18)) break;            // hang-safety
      __builtin_amdgcn_s_sleep(1);
      v1 = __hip_atomic_load(s1p, __ATOMIC_RELAXED, __HIP_MEMORY_SCOPE_AGENT);
    }
    *(u64*)(hs1 + wba) = v1;
    sync_lds();                                // sync B: z0 + hs1 ready

    // ---- L0 combine + EARLY publish (wave0 lanes 0..7; one 16B coalesced store) ----
    if (tid < 8) {
      if (r < SEQ) {
        const float zi = z0buf[tid * 4 + 0] + bsq0 + wx0q0 * x0v + wx1q0 * x1v;
        const float zf = z0buf[tid * 4 + 1] + bsq1 + wx0q1 * x0v + wx1q1 * x1v;
        const float zg = z0buf[tid * 4 + 2] + bsq2 + wx0q2 * x0v + wx1q2 * x1v;
        const float zo = z0buf[tid * 4 + 3] + bsq3 + wx0q3 * x0v + wx1q3 * x1v;
        const float ig = sigm(zi), fg = sigm(zf), gg = tanh_(zg), og = sigm(zo);
        cst = fg * cst + ig * gg;
        const float hv = og * tanh_(cst);
        const f16 hh = (f16)hv;
        const u32 hbits = (u32)__builtin_bit_cast(u16, hh);
        const u32 nb = __shfl(hbits, tid | 1);        // partner within lanes 0..7
        if (!(tid & 1)) {
          const u32 pairv = hbits | (nb << 16);
          __hip_atomic_store((u32*)(h0b + (size_t)(r + 1) * H) + (b * 4 + (tid >> 1)),
                             pairv, __ATOMIC_RELAXED, __HIP_MEMORY_SCOPE_AGENT);
        }
      }
    }

    // ---- PRE-ISSUE next round's h0 poll load (flies across phase B + syncC) ----
    if (r < SEQ) {
      v0 = __hip_atomic_load((const u64*)h0b + (size_t)(r + 1) * (H / 4) + tid,
                             __ATOMIC_RELAXED, __HIP_MEMORY_SCOPE_AGENT);
    }

    // ---- phase B: z1 = Wih1 · h0_r + Whh1 · h1_{r-1} (128 dot2/lane) ----
    float a1[4] = {0.f, 0.f, 0.f, 0.f};
    #pragma unroll
    for (int c = 0; c < 4; ++c) {
      const uint4 u0 = *(const uint4*)(hs0 + lane * 80 + c * 16);
      const uint4 u1 = *(const uint4*)(hs1 + lane * 80 + c * 16);
      #pragma unroll
      for (int m = 0; m < 4; ++m) {
        a1[m] = dot2(wgt[m][1][4 * c + 0], u0.x, a1[m]);
        a1[m] = dot2(wgt[m][1][4 * c + 1], u0.y, a1[m]);
        a1[m] = dot2(wgt[m][1][4 * c + 2], u0.z, a1[m]);
        a1[m] = dot2(wgt[m][1][4 * c + 3], u0.w, a1[m]);
        a1[m] = dot2(wgt[m][2][4 * c + 0], u1.x, a1[m]);
        a1[m] = dot2(wgt[m][2][4 * c + 1], u1.y, a1[m]);
        a1[m] = dot2(wgt[m][2][4 * c + 2], u1.z, a1[m]);
        a1[m] = dot2(wgt[m][2][4 * c + 3], u1.w, a1[m]);
      }
    }
    {
      const float s0 = wave_reduce63(a1[0]);
      const float s1 = wave_reduce63(a1[1]);
      const float s2 = wave_reduce63(a1[2]);
      const float s3 = wave_reduce63(a1[3]);
      if (lane == 63) {
        z1buf[4 * wave + 0] = s0;
        z1buf[4 * wave + 1] = s1;
        z1buf[4 * wave + 2] = s2;
        z1buf[4 * wave + 3] = s3;
      }
    }
    sync_lds();                                // sync C: z1 ready (v0 still in flight)

    // ---- L1 combine + publish (wave0 lanes 8..15; one 16B coalesced store) ----
    if (tid >= 8 && tid < 16) {
      if (r >= 1) {
        const int j = tid - 8;
        const float zi = z1buf[j * 4 + 0] + bsq0;
        const float zf = z1buf[j * 4 + 1] + bsq1;
        const float zg = z1buf[j * 4 + 2] + bsq2;
        const float zo = z1buf[j * 4 + 3] + bsq3;
        const float ig = sigm(zi), fg = sigm(zf), gg = tanh_(zg), og = sigm(zo);
        cst = fg * cst + ig * gg;
        const float hv = og * tanh_(cst);
        const f16 hh = (f16)hv;
        const u32 hbits = (u32)__builtin_bit_cast(u16, hh);
        const u32 nb = __shfl(hbits, tid | 1);        // partner within lanes 8..15
        if (!(tid & 1)) {
          const u32 pairv = hbits | (nb << 16);
          __hip_atomic_store((u32*)(h1b + (size_t)r * H) + (b * 4 + (j >> 1)),
                             pairv, __ATOMIC_RELAXED, __HIP_MEMORY_SCOPE_AGENT);
        }
      }
    }
    // next round's sync A orders the z/hs buffer reuse
  }
}

// ---------------- final linear: out = W_lin @ h1_SEQ + b_lin ----------------
__global__ void lstm_fin(const unsigned char* __restrict__ wsb,
                         const float* __restrict__ Wlin,   // [2,H]
                         const float* __restrict__ blin,   // [2]
                         float* __restrict__ out)
{
  __shared__ float red[2][4];
  const f16* h1 = (const f16*)(wsb + H1_OFF) + (size_t)SEQ * H;
  const int tid = threadIdx.x;  // 256 threads
  float p0 = 0.f, p1 = 0.f;
  for (int k = tid; k < H; k += 256) {
    const float h = (float)h1[k];
    p0 += h * Wlin[k];
    p1 += h * Wlin[H + k];
  }
  p0 = wave_reduce63(p0);
  p1 = wave_reduce63(p1);
  const int wv = tid >> 6, ln = tid & 63;
  if (ln == 63) { red[0][wv] = p0; red[1][wv] = p1; }
  __syncthreads();
  if (tid == 0) {
    out[0] = blin[0] + red[0][0] + red[0][1] + red[0][2] + red[0][3];
    out[1] = blin[1] + red[1][0] + red[1][1] + red[1][2] + red[1][3];
  }
}

extern "C" void kernel_launch(void* const* d_in, const int* in_sizes, int n_in,
                              void* d_out, int out_size, void* d_ws, size_t ws_size,
                              hipStream_t stream) {
  const float* xin  = (const float*)d_in[0];
  const float* h0in = (const float*)d_in[1];
  const float* c0in = (const float*)d_in[2];
  const float* Wih0 = (const float*)d_in[3];
  const float* Whh0 = (const float*)d_in[4];
  const float* bih0 = (const float*)d_in[5];
  const float* bhh0 = (const float*)d_in[6];
  const float* Wih1 = (const float*)d_in[7];
  const float* Whh1 = (const float*)d_in[8];
  const float* bih1 = (const float*)d_in[9];
  const float* bhh1 = (const float*)d_in[10];
  const float* Wlin = (const float*)d_in[11];
  const float* blin = (const float*)d_in[12];
  unsigned char* wsb = (unsigned char*)d_ws;

  if (ws_size < WS_NEED) return;  // fail visibly (output stays poisoned)

  lstm_init<<<dim3((PER_BUF_U32 + 255) / 256), dim3(256), 0, stream>>>(h0in, wsb);
  lstm_pers<<<dim3(NB), dim3(NT), 0, stream>>>(xin, c0in, Wih0, Whh0, bih0, bhh0,
                                               Wih1, Whh1, bih1, bhh1, wsb);
  lstm_fin<<<dim3(1), dim3(256), 0, stream>>>(wsb, Wlin, blin, (float*)d_out);
}